// Round 4
// baseline (1628.823 us; speedup 1.0000x reference)
//
#include <hip/hip_runtime.h>
#include <math.h>

#define NL 6
#define ND 512
#define NFF 2048

// ---------- wave helpers ----------
__device__ __forceinline__ float wave_sum(float v) {
    v += __shfl_down(v, 32, 64);
    v += __shfl_down(v, 16, 64);
    v += __shfl_down(v, 8, 64);
    v += __shfl_down(v, 4, 64);
    v += __shfl_down(v, 2, 64);
    v += __shfl_down(v, 1, 64);
    return v;
}
__device__ __forceinline__ float wave_sum_all(float v) {
    v += __shfl_xor(v, 32, 64);
    v += __shfl_xor(v, 16, 64);
    v += __shfl_xor(v, 8, 64);
    v += __shfl_xor(v, 4, 64);
    v += __shfl_xor(v, 2, 64);
    v += __shfl_xor(v, 1, 64);
    return v;
}

__device__ __forceinline__ float dot8(const float* a, int lane, float4 w1, float4 w2) {
    int d0 = lane * 8;
    float4 x1 = *(const float4*)(a + d0);
    float4 x2 = *(const float4*)(a + d0 + 4);
    return x1.x*w1.x + x1.y*w1.y + x1.z*w1.z + x1.w*w1.w
         + x2.x*w2.x + x2.y*w2.y + x2.z*w2.z + x2.w*w2.w;
}
__device__ __forceinline__ float dotg(const float* __restrict__ a,
                                      const float* __restrict__ b, int lane) {
    int d0 = lane * 8;
    float4 a1 = *(const float4*)(a + d0);
    float4 a2 = *(const float4*)(a + d0 + 4);
    float4 b1 = *(const float4*)(b + d0);
    float4 b2 = *(const float4*)(b + d0 + 4);
    return a1.x*b1.x + a1.y*b1.y + a1.z*b1.z + a1.w*b1.w
         + a2.x*b2.x + a2.y*b2.y + a2.z*b2.z + a2.w*b2.w;
}

// LN stats over a 512-row held as 8 floats/lane across one wave
__device__ __forceinline__ void stats8(float4 f1, float4 f2, float& mu, float& inv) {
    float s = f1.x+f1.y+f1.z+f1.w + f2.x+f2.y+f2.z+f2.w;
    s = wave_sum_all(s);
    mu = s * (1.f/512.f);
    float q = (f1.x-mu)*(f1.x-mu) + (f1.y-mu)*(f1.y-mu) + (f1.z-mu)*(f1.z-mu) + (f1.w-mu)*(f1.w-mu)
            + (f2.x-mu)*(f2.x-mu) + (f2.y-mu)*(f2.y-mu) + (f2.z-mu)*(f2.z-mu) + (f2.w-mu)*(f2.w-mu);
    q = wave_sum_all(q);
    inv = rsqrtf(q * (1.f/512.f) + 1e-5f);
}
__device__ __forceinline__ void ln_apply(float4& f1, float4& f2, float mu, float inv,
                                         const float* __restrict__ w,
                                         const float* __restrict__ b, int d0) {
    float4 w1 = *(const float4*)(w + d0), w2 = *(const float4*)(w + d0 + 4);
    float4 b1 = *(const float4*)(b + d0), b2 = *(const float4*)(b + d0 + 4);
    f1.x = (f1.x-mu)*inv*w1.x + b1.x; f1.y = (f1.y-mu)*inv*w1.y + b1.y;
    f1.z = (f1.z-mu)*inv*w1.z + b1.z; f1.w = (f1.w-mu)*inv*w1.w + b1.w;
    f2.x = (f2.x-mu)*inv*w2.x + b2.x; f2.y = (f2.y-mu)*inv*w2.y + b2.y;
    f2.z = (f2.z-mu)*inv*w2.z + b2.z; f2.w = (f2.w-mu)*inv*w2.w + b2.w;
}

// ---------- grid barrier: 2-level, monotonic counters, fence-based ----------
// bar[sub*16] : 8 sub-group counters (64B apart); bar[128]: top; bar[144]: gen
__device__ __forceinline__ void gbar(unsigned* bar, int k) {
    __threadfence();          // flush this thread's writes to device scope
    __syncthreads();
    if (threadIdx.x == 0) {
        int sub = blockIdx.x & 7;
        unsigned v = __hip_atomic_fetch_add(&bar[sub*16], 1u, __ATOMIC_RELAXED, __HIP_MEMORY_SCOPE_AGENT);
        if (v == 32u*(unsigned)(k+1) - 1u) {
            unsigned tt = __hip_atomic_fetch_add(&bar[128], 1u, __ATOMIC_RELAXED, __HIP_MEMORY_SCOPE_AGENT);
            if (tt == 8u*(unsigned)(k+1) - 1u)
                __hip_atomic_fetch_add(&bar[144], 1u, __ATOMIC_RELEASE, __HIP_MEMORY_SCOPE_AGENT);
        }
        while (__hip_atomic_load(&bar[144], __ATOMIC_RELAXED, __HIP_MEMORY_SCOPE_AGENT) < (unsigned)(k+1))
            __builtin_amdgcn_s_sleep(4);
    }
    __syncthreads();
    __threadfence();          // acquire: invalidate stale cached data
}

__global__ __launch_bounds__(256, 2)
void fused_persistent(const float* __restrict__ features, const float* __restrict__ role,
                      const float* __restrict__ in_w,  const float* __restrict__ in_b,
                      const float* __restrict__ out_w, const float* __restrict__ out_b,
                      const float* __restrict__ ln1_w, const float* __restrict__ ln1_b,
                      const float* __restrict__ ln2_w, const float* __restrict__ ln2_b,
                      const float* __restrict__ ln3_w, const float* __restrict__ ln3_b,
                      const float* __restrict__ ln4_w, const float* __restrict__ ln4_b,
                      const float* __restrict__ f1_w1, const float* __restrict__ f1_b1,
                      const float* __restrict__ f1_w2, const float* __restrict__ f1_b2,
                      const float* __restrict__ f2_w1, const float* __restrict__ f2_b1,
                      const float* __restrict__ f2_w2, const float* __restrict__ f2_b2,
                      const float* __restrict__ a1_w,  const float* __restrict__ a1_b,
                      const float* __restrict__ a2_w,  const float* __restrict__ a2_b,
                      unsigned* bar, float* wsf, float* __restrict__ outp)
{
    __shared__ float lds[18432];   // 72 KB, reused per phase
    __shared__ float sred[16];
    const int t = threadIdx.x, bid = blockIdx.x;
    const int wv = t >> 6, lane = t & 63;
    const int gw = bid * 4 + wv;   // global wave id 0..1023
    const int d0 = lane * 8;
    int bk = 0;

    float* qkv_pre  = wsf;                   // [6][35][1536]
    float* msg_pre  = qkv_pre + 322560;      // [6][5][512]
    float* aggv_pre = msg_pre + 15360;       // [6][512]
    float* qkv0     = aggv_pre + 3072;       // [7][1536]
    float* msg0     = qkv0 + 10752;          // [6][512]
    float* aggn     = msg0 + 3072;           // [512]
    float* hbuf     = aggn + 512;            // [7][2048]
    float* xlnws    = hbuf + 14336;          // [7][512]
    float* ffA      = xlnws + 3584;          // [7][512]
    float* ffB      = ffA + 3584;            // [7][512]

    // ================= P1: qkv for batches 1..5, ALL 6 layers =================
    // LDS: 35 src rows (features + role)
    for (int i = t; i < 35*ND; i += 256) {
        int m = i >> 9, d = i & 511;
        int b = m / 7 + 1, s = m - (m/7)*7;
        float v = features[(b*7+s)*ND + d];
        if (s > 0) v += role[(b*6 + s-1)*ND + d];
        lds[i] = v;
    }
    __syncthreads();
    for (int k = 0; k < 9; k++) {
        int p = gw + (k << 10);   // 0..9215
        int l, e; bool kv;
        if (p < 6144) { l = p >> 10; e = 512 + (p & 1023); kv = true; }
        else { int q = p - 6144; l = q >> 9; e = q & 511; kv = false; }
        const float* wr = in_w + ((size_t)l*1536 + e)*ND + d0;
        float4 w1 = *(const float4*)wr, w2 = *(const float4*)(wr + 4);
        float bias = in_b[l*1536 + e];
        if (kv) {
            for (int m = 0; m < 35; m++) {
                float a = dot8(&lds[m*ND], lane, w1, w2);
                a = wave_sum(a);
                if (lane == 0) qkv_pre[((size_t)l*35 + m)*1536 + e] = a + bias;
            }
        } else {
            for (int bb = 0; bb < 5; bb++) {
                int m = bb * 7;  // s=0 rows only (Q needed just for s=0)
                float a = dot8(&lds[m*ND], lane, w1, w2);
                a = wave_sum(a);
                if (lane == 0) qkv_pre[((size_t)l*35 + m)*1536 + e] = a + bias;
            }
        }
    }
    gbar(bar, bk++);

    // ================= P2: attention + msg row (s=0) for b=1..5, all layers =====
    if (bid < 240) {
        int g = bid >> 3, sub = bid & 7;
        int l = g / 5, b = g - l*5 + 1;
        float* kl = lds;            // 7*512
        float* vl = lds + 3584;     // 7*512
        float* ql = lds + 7168;     // 512
        float* cl = lds + 7680;     // 512
        float* at = lds + 8192;     // 56
        size_t base = ((size_t)l*35 + (b-1)*7) * 1536;
        for (int i = t; i < 3584; i += 256) {
            int s = i >> 9, d = i & 511;
            kl[i] = qkv_pre[base + (size_t)s*1536 + 512 + d];
            vl[i] = qkv_pre[base + (size_t)s*1536 + 1024 + d];
        }
        for (int i = t; i < 512; i += 256) ql[i] = qkv_pre[base + i];
        __syncthreads();
        if (t < 56) {
            int h = t / 7, kk = t - (t/7)*7;
            float a = 0.f;
            for (int d = 0; d < 64; d++) a += ql[h*64 + d] * kl[kk*512 + h*64 + d];
            at[t] = a * 0.125f;
        }
        __syncthreads();
        if (t < 8) {
            float m = -1e30f;
            for (int j = 0; j < 7; j++) m = fmaxf(m, at[t*7 + j]);
            float e[7], ss = 0.f;
            for (int j = 0; j < 7; j++) { e[j] = expf(at[t*7 + j] - m); ss += e[j]; }
            float inv = 1.f / ss;
            for (int j = 0; j < 7; j++) at[t*7 + j] = e[j] * inv;
        }
        __syncthreads();
        for (int i = t; i < 512; i += 256) {
            int h = i >> 6;
            float a = 0.f;
            for (int kk = 0; kk < 7; kk++) a += at[h*7 + kk] * vl[kk*512 + i];
            cl[i] = a;
        }
        __syncthreads();
        for (int i = 0; i < 16; i++) {
            int e = sub*64 + wv*16 + i;
            const float* wr = out_w + ((size_t)l*512 + e)*ND + d0;
            float4 w1 = *(const float4*)wr, w2 = *(const float4*)(wr + 4);
            float a = dot8(cl, lane, w1, w2);
            a = wave_sum(a);
            if (lane == 0) msg_pre[((size_t)l*5 + b-1)*512 + e] = a + out_b[l*512 + e];
        }
    }
    gbar(bar, bk++);

    // ================= P3: agg_verb for all layers =================
    for (int k = 0; k < 3; k++) {
        int p = gw + (k << 10);   // 0..3071
        int l = p >> 9, j = p & 511;
        const float* wj = a1_w + (size_t)l*1310720 + (size_t)j*2560;
        float a = 0.f;
        for (int c = 0; c < 5; c++)
            a += dotg(msg_pre + ((size_t)l*5 + c)*512, wj + c*512, lane);
        a = wave_sum(a);
        if (lane == 0) aggv_pre[l*512 + j] = 1.f / (1.f + expf(-(a + a1_b[l*512 + j])));
    }
    gbar(bar, bk++);

    // ================= sequential layer chain (batch 0) =================
    const float* ffprev = nullptr;
    #pragma unroll 1
    for (int l = 0; l < NL; l++) {
        float* ffcur = (l & 1) ? ffB : ffA;

        // ---- S1: build src rows (cur + role) in LDS, then qkv b0 ----
        for (int rr = wv; rr < 7; rr += 4) {
            float4 f1, f2;
            if (l == 0) {
                const float* sp = features + rr*ND + d0;
                f1 = *(const float4*)sp; f2 = *(const float4*)(sp + 4);
            } else {
                const float* sp = ffprev + rr*ND + d0;
                f1 = *(const float4*)sp; f2 = *(const float4*)(sp + 4);
                float mu, inv; stats8(f1, f2, mu, inv);
                const float* w  = ((rr == 0) ? ln4_w : ln2_w) + (size_t)(l-1)*ND;
                const float* bb = ((rr == 0) ? ln4_b : ln2_b) + (size_t)(l-1)*ND;
                ln_apply(f1, f2, mu, inv, w, bb, d0);
            }
            if (rr > 0) {
                const float* rp = role + (size_t)(rr-1)*ND + d0;
                float4 r1 = *(const float4*)rp, r2 = *(const float4*)(rp + 4);
                f1.x += r1.x; f1.y += r1.y; f1.z += r1.z; f1.w += r1.w;
                f2.x += r2.x; f2.y += r2.y; f2.z += r2.z; f2.w += r2.w;
            }
            *(float4*)&lds[rr*ND + d0] = f1;
            *(float4*)&lds[rr*ND + d0 + 4] = f2;
        }
        __syncthreads();
        for (int e = gw; e < 1536; e += 1024) {
            const float* wr = in_w + ((size_t)l*1536 + e)*ND + d0;
            float4 w1 = *(const float4*)wr, w2 = *(const float4*)(wr + 4);
            float bias = in_b[l*1536 + e];
            for (int s = 0; s < 7; s++) {
                float a = dot8(&lds[s*ND], lane, w1, w2);
                a = wave_sum(a);
                if (lane == 0) qkv0[s*1536 + e] = a + bias;
            }
        }
        gbar(bar, bk++);

        // ---- S2: attention b0 + msg rows 1..6 ----
        {
            float* kl = lds;             // 7*512
            float* vl = lds + 3584;      // 7*512
            float* ql = lds + 7168;      // 6*512 (q rows 1..6)
            float* cl = lds + 10240;     // 6*512 (ctx rows 1..6)
            float* at = lds + 13312;     // 6*56
            for (int i = t; i < 3584; i += 256) {
                int s = i >> 9, d = i & 511;
                kl[i] = qkv0[s*1536 + 512 + d];
                vl[i] = qkv0[s*1536 + 1024 + d];
            }
            for (int i = t; i < 3072; i += 256) {
                int s = (i >> 9) + 1;
                ql[i] = qkv0[s*1536 + (i & 511)];
            }
            __syncthreads();
            for (int idx = t; idx < 336; idx += 256) {
                int qr = idx / 56, rem = idx - qr*56;
                int h = rem / 7, kk = rem - (rem/7)*7;
                float a = 0.f;
                for (int d = 0; d < 64; d++) a += ql[qr*512 + h*64 + d] * kl[kk*512 + h*64 + d];
                at[idx] = a * 0.125f;
            }
            __syncthreads();
            if (t < 48) {
                int qr = t >> 3, h = t & 7;
                float* ap = at + qr*56 + h*7;
                float m = -1e30f;
                for (int j = 0; j < 7; j++) m = fmaxf(m, ap[j]);
                float e[7], ss = 0.f;
                for (int j = 0; j < 7; j++) { e[j] = expf(ap[j] - m); ss += e[j]; }
                float inv = 1.f / ss;
                for (int j = 0; j < 7; j++) ap[j] = e[j] * inv;
            }
            __syncthreads();
            for (int i = t; i < 3072; i += 256) {
                int qr = i >> 9, d = i & 511, h = d >> 6;
                const float* ap = at + qr*56 + h*7;
                float a = 0.f;
                for (int kk = 0; kk < 7; kk++) a += ap[kk] * vl[kk*512 + d];
                cl[i] = a;
            }
            __syncthreads();
            for (int i = 0; i < 3; i++) {
                int o = bid*12 + wv*3 + i;      // 0..3071
                int s = (o >> 9) + 1, e = o & 511;
                const float* wr = out_w + ((size_t)l*512 + e)*ND + d0;
                float4 w1 = *(const float4*)wr, w2 = *(const float4*)(wr + 4);
                float a = dot8(&cl[(s-1)*512], lane, w1, w2);
                a = wave_sum(a);
                if (lane == 0) msg0[(s-1)*512 + e] = a + out_b[l*512 + e];
            }
        }
        gbar(bar, bk++);

        // ---- S3: agg_noun ----
        {
            int j = bid*2 + (wv >> 1), half = wv & 1;
            const float* wj = a2_w + (size_t)l*1572864 + (size_t)j*3072 + half*1536;
            float a = 0.f;
            for (int c = 0; c < 3; c++)
                a += dotg(msg0 + (half*3 + c)*512, wj + c*512, lane);
            a = wave_sum(a);
            if (lane == 0) sred[wv] = a;
        }
        __syncthreads();
        if (t == 0) {
            int j0 = bid*2;
            aggn[j0]     = 1.f / (1.f + expf(-(sred[0] + sred[1] + a2_b[l*512 + j0])));
            aggn[j0 + 1] = 1.f / (1.f + expf(-(sred[2] + sred[3] + a2_b[l*512 + j0 + 1])));
        }
        gbar(bar, bk++);

        // ---- S4: build xln rows in LDS; ffa ----
        for (int rr = wv; rr < 7; rr += 4) {
            float4 f1, f2;
            if (l == 0) {
                const float* sp = features + rr*ND + d0;
                f1 = *(const float4*)sp; f2 = *(const float4*)(sp + 4);
            } else {
                const float* sp = ffprev + rr*ND + d0;
                f1 = *(const float4*)sp; f2 = *(const float4*)(sp + 4);
                float mu, inv; stats8(f1, f2, mu, inv);
                const float* w  = ((rr == 0) ? ln4_w : ln2_w) + (size_t)(l-1)*ND;
                const float* bb = ((rr == 0) ? ln4_b : ln2_b) + (size_t)(l-1)*ND;
                ln_apply(f1, f2, mu, inv, w, bb, d0);
            }
            const float* ag = (rr == 0) ? aggn : (aggv_pre + l*512);
            float4 g1 = *(const float4*)(ag + d0), g2 = *(const float4*)(ag + d0 + 4);
            f1.x += g1.x; f1.y += g1.y; f1.z += g1.z; f1.w += g1.w;
            f2.x += g2.x; f2.y += g2.y; f2.z += g2.z; f2.w += g2.w;
            float mu, inv; stats8(f1, f2, mu, inv);
            const float* w  = ((rr == 0) ? ln3_w : ln1_w) + (size_t)l*ND;
            const float* bb = ((rr == 0) ? ln3_b : ln1_b) + (size_t)l*ND;
            ln_apply(f1, f2, mu, inv, w, bb, d0);
            *(float4*)&lds[rr*ND + d0] = f1;
            *(float4*)&lds[rr*ND + d0 + 4] = f2;
        }
        __syncthreads();
        if (bid == 0) for (int i = t; i < 3584; i += 256) xlnws[i] = lds[i];
        for (int i = 0; i < 2; i++) {
            int f = bid*8 + wv*2 + i;    // 0..2047
            const float* wr1 = f1_w1 + ((size_t)l*2048 + f)*ND + d0;  // rows 1..6
            float4 p1 = *(const float4*)wr1, p2 = *(const float4*)(wr1 + 4);
            const float* wr2 = f2_w1 + ((size_t)l*2048 + f)*ND + d0;  // row 0
            float4 q1 = *(const float4*)wr2, q2 = *(const float4*)(wr2 + 4);
            float a = dot8(&lds[0], lane, q1, q2);
            a = wave_sum(a);
            if (lane == 0) hbuf[f] = fmaxf(a + f2_b1[l*2048 + f], 0.f);
            for (int r = 1; r < 7; r++) {
                float b = dot8(&lds[r*ND], lane, p1, p2);
                b = wave_sum(b);
                if (lane == 0) hbuf[r*2048 + f] = fmaxf(b + f1_b1[l*2048 + f], 0.f);
            }
        }
        gbar(bar, bk++);

        // ---- S5: ffb (+ residual) ----
        {
            int d = bid*2 + (wv >> 1);
            int rs = (wv & 1) ? 4 : 0, re = (wv & 1) ? 7 : 4;
            for (int r = rs; r < re; r++) {
                const float* W = ((r == 0) ? f2_w2 : f1_w2) + (size_t)l*1048576 + (size_t)d*2048;
                float a = 0.f;
                for (int c = 0; c < 4; c++)
                    a += dotg(hbuf + r*2048 + c*512, W + c*512, lane);
                a = wave_sum(a);
                if (lane == 0) {
                    float bias = (r == 0) ? f2_b2[l*512 + d] : f1_b2[l*512 + d];
                    ffcur[r*512 + d] = xlnws[r*512 + d] + a + bias;
                }
            }
        }
        ffprev = ffcur;
        gbar(bar, bk++);
    }

    // ================= F: final LN -> d_out =================
    if (bid < 7) {
        int r = bid;
        float x0 = ffprev[r*ND + t], x1 = ffprev[r*ND + 256 + t];
        float v = wave_sum(x0 + x1);
        if (lane == 0) sred[wv] = v;
        __syncthreads();
        float mu = (sred[0] + sred[1] + sred[2] + sred[3]) * (1.f/512.f);
        __syncthreads();
        float e0 = x0 - mu, e1 = x1 - mu;
        v = wave_sum(e0*e0 + e1*e1);
        if (lane == 0) sred[wv] = v;
        __syncthreads();
        float var = (sred[0] + sred[1] + sred[2] + sred[3]) * (1.f/512.f);
        float inv = rsqrtf(var + 1e-5f);
        const float* w  = ((r == 0) ? ln4_w : ln2_w) + (size_t)(NL-1)*ND;
        const float* bb = ((r == 0) ? ln4_b : ln2_b) + (size_t)(NL-1)*ND;
        outp[r*ND + t]       = e0*inv*w[t]       + bb[t];
        outp[r*ND + 256 + t] = e1*inv*w[256 + t] + bb[256 + t];
    }
}

extern "C" void kernel_launch(void* const* d_in, const int* in_sizes, int n_in,
                              void* d_out, int out_size, void* d_ws, size_t ws_size,
                              hipStream_t stream) {
    const float* features = (const float*)d_in[0];
    const float* role     = (const float*)d_in[1];
    const float* in_w  = (const float*)d_in[2];
    const float* in_b  = (const float*)d_in[3];
    const float* out_w = (const float*)d_in[4];
    const float* out_b = (const float*)d_in[5];
    const float* ln1_w = (const float*)d_in[6];
    const float* ln1_b = (const float*)d_in[7];
    const float* ln2_w = (const float*)d_in[8];
    const float* ln2_b = (const float*)d_in[9];
    const float* ln3_w = (const float*)d_in[10];
    const float* ln3_b = (const float*)d_in[11];
    const float* ln4_w = (const float*)d_in[12];
    const float* ln4_b = (const float*)d_in[13];
    const float* f1_w1 = (const float*)d_in[14];
    const float* f1_b1 = (const float*)d_in[15];
    const float* f1_w2 = (const float*)d_in[16];
    const float* f1_b2 = (const float*)d_in[17];
    const float* f2_w1 = (const float*)d_in[18];
    const float* f2_b1 = (const float*)d_in[19];
    const float* f2_w2 = (const float*)d_in[20];
    const float* f2_b2 = (const float*)d_in[21];
    const float* a1_w  = (const float*)d_in[22];
    const float* a1_b  = (const float*)d_in[23];
    const float* a2_w  = (const float*)d_in[24];
    const float* a2_b  = (const float*)d_in[25];

    // barrier state: first 1024 bytes of ws, zeroed every call (monotonic counters)
    hipMemsetAsync(d_ws, 0, 1024, stream);
    unsigned* bar = (unsigned*)d_ws;
    float* wsf = (float*)d_ws + 256;

    fused_persistent<<<256, 256, 0, stream>>>(
        features, role, in_w, in_b, out_w, out_b,
        ln1_w, ln1_b, ln2_w, ln2_b, ln3_w, ln3_b, ln4_w, ln4_b,
        f1_w1, f1_b1, f1_w2, f1_b2, f2_w1, f2_b1, f2_w2, f2_b2,
        a1_w, a1_b, a2_w, a2_b,
        bar, wsf, (float*)d_out);
}

// Round 5
// 785.381 us; speedup vs baseline: 2.0739x; 2.0739x over previous
//
#include <hip/hip_runtime.h>
#include <math.h>

#define NL 6
#define ND 512
#define NFF 2048

// ---------- coherent (L2-bypassing, sc0 sc1) scalar access: safe cross-XCD ----------
__device__ __forceinline__ float cload(const float* p) {
    return __hip_atomic_load(p, __ATOMIC_RELAXED, __HIP_MEMORY_SCOPE_AGENT);
}
__device__ __forceinline__ void cstore(float* p, float v) {
    __hip_atomic_store(p, v, __ATOMIC_RELAXED, __HIP_MEMORY_SCOPE_AGENT);
}

// ---------- wave helpers ----------
__device__ __forceinline__ float wave_sum(float v) {
    v += __shfl_down(v, 32, 64);
    v += __shfl_down(v, 16, 64);
    v += __shfl_down(v, 8, 64);
    v += __shfl_down(v, 4, 64);
    v += __shfl_down(v, 2, 64);
    v += __shfl_down(v, 1, 64);
    return v;
}
__device__ __forceinline__ float wave_sum_all(float v) {
    v += __shfl_xor(v, 32, 64);
    v += __shfl_xor(v, 16, 64);
    v += __shfl_xor(v, 8, 64);
    v += __shfl_xor(v, 4, 64);
    v += __shfl_xor(v, 2, 64);
    v += __shfl_xor(v, 1, 64);
    return v;
}

// lane handles dwords [d0, d0+3] and [256+d0, 256+d0+3] where d0 = 4*lane.
// 16B lane stride => conflict-free ds_read_b128.
__device__ __forceinline__ float dot8L(const float* a, int d0, float4 w1, float4 w2) {
    float4 x1 = *(const float4*)(a + d0);
    float4 x2 = *(const float4*)(a + 256 + d0);
    return x1.x*w1.x + x1.y*w1.y + x1.z*w1.z + x1.w*w1.w
         + x2.x*w2.x + x2.y*w2.y + x2.z*w2.z + x2.w*w2.w;
}
__device__ __forceinline__ void cload8(const float* p, int d0, float4& f1, float4& f2) {
    f1.x = cload(p + d0);           f1.y = cload(p + d0 + 1);
    f1.z = cload(p + d0 + 2);       f1.w = cload(p + d0 + 3);
    f2.x = cload(p + 256 + d0);     f2.y = cload(p + 256 + d0 + 1);
    f2.z = cload(p + 256 + d0 + 2); f2.w = cload(p + 256 + d0 + 3);
}
__device__ __forceinline__ float dotc(const float* ac, const float* w, int d0) {
    float4 w1 = *(const float4*)(w + d0), w2 = *(const float4*)(w + 256 + d0);
    float4 a1, a2; cload8(ac, d0, a1, a2);
    return a1.x*w1.x + a1.y*w1.y + a1.z*w1.z + a1.w*w1.w
         + a2.x*w2.x + a2.y*w2.y + a2.z*w2.z + a2.w*w2.w;
}

// LN stats over a 512-row held as 8 floats/lane across one wave (bijective partition)
__device__ __forceinline__ void stats8(float4 f1, float4 f2, float& mu, float& inv) {
    float s = f1.x+f1.y+f1.z+f1.w + f2.x+f2.y+f2.z+f2.w;
    s = wave_sum_all(s);
    mu = s * (1.f/512.f);
    float q = (f1.x-mu)*(f1.x-mu) + (f1.y-mu)*(f1.y-mu) + (f1.z-mu)*(f1.z-mu) + (f1.w-mu)*(f1.w-mu)
            + (f2.x-mu)*(f2.x-mu) + (f2.y-mu)*(f2.y-mu) + (f2.z-mu)*(f2.z-mu) + (f2.w-mu)*(f2.w-mu);
    q = wave_sum_all(q);
    inv = rsqrtf(q * (1.f/512.f) + 1e-5f);
}
__device__ __forceinline__ void ln_apply(float4& f1, float4& f2, float mu, float inv,
                                         const float* __restrict__ w,
                                         const float* __restrict__ b, int d0) {
    float4 w1 = *(const float4*)(w + d0), w2 = *(const float4*)(w + 256 + d0);
    float4 b1 = *(const float4*)(b + d0), b2 = *(const float4*)(b + 256 + d0);
    f1.x = (f1.x-mu)*inv*w1.x + b1.x; f1.y = (f1.y-mu)*inv*w1.y + b1.y;
    f1.z = (f1.z-mu)*inv*w1.z + b1.z; f1.w = (f1.w-mu)*inv*w1.w + b1.w;
    f2.x = (f2.x-mu)*inv*w2.x + b2.x; f2.y = (f2.y-mu)*inv*w2.y + b2.y;
    f2.z = (f2.z-mu)*inv*w2.z + b2.z; f2.w = (f2.w-mu)*inv*w2.w + b2.w;
}

// ---------- grid barrier: NO cache maintenance. Data goes through sc1 path; here we
// only drain vmcnt (all sc1 stores acked at coherent point) and do relaxed atomics.
__device__ __forceinline__ void gbar(unsigned* bar, int k) {
    asm volatile("s_waitcnt vmcnt(0) lgkmcnt(0)" ::: "memory");
    __syncthreads();
    if (threadIdx.x == 0) {
        int sub = blockIdx.x & 7;
        unsigned v = __hip_atomic_fetch_add(&bar[sub*32], 1u, __ATOMIC_RELAXED, __HIP_MEMORY_SCOPE_AGENT);
        if (v == 32u*(unsigned)(k+1) - 1u) {
            unsigned tt = __hip_atomic_fetch_add(&bar[512], 1u, __ATOMIC_RELAXED, __HIP_MEMORY_SCOPE_AGENT);
            if (tt == 8u*(unsigned)(k+1) - 1u)
                __hip_atomic_store(&bar[768], (unsigned)(k+1), __ATOMIC_RELAXED, __HIP_MEMORY_SCOPE_AGENT);
        }
        while (__hip_atomic_load(&bar[768], __ATOMIC_RELAXED, __HIP_MEMORY_SCOPE_AGENT) < (unsigned)(k+1))
            __builtin_amdgcn_s_sleep(2);
    }
    __syncthreads();
}

__global__ __launch_bounds__(256, 2)
void fused_persistent(const float* __restrict__ features, const float* __restrict__ role,
                      const float* __restrict__ in_w,  const float* __restrict__ in_b,
                      const float* __restrict__ out_w, const float* __restrict__ out_b,
                      const float* __restrict__ ln1_w, const float* __restrict__ ln1_b,
                      const float* __restrict__ ln2_w, const float* __restrict__ ln2_b,
                      const float* __restrict__ ln3_w, const float* __restrict__ ln3_b,
                      const float* __restrict__ ln4_w, const float* __restrict__ ln4_b,
                      const float* __restrict__ f1_w1, const float* __restrict__ f1_b1,
                      const float* __restrict__ f1_w2, const float* __restrict__ f1_b2,
                      const float* __restrict__ f2_w1, const float* __restrict__ f2_b1,
                      const float* __restrict__ f2_w2, const float* __restrict__ f2_b2,
                      const float* __restrict__ a1_w,  const float* __restrict__ a1_b,
                      const float* __restrict__ a2_w,  const float* __restrict__ a2_b,
                      unsigned* bar, float* wsf, float* __restrict__ outp)
{
    __shared__ float lds[18432];   // 72 KB, reused per phase
    __shared__ float sred[16];
    const int t = threadIdx.x, bid = blockIdx.x;
    const int wv = t >> 6, lane = t & 63;
    const int gw = bid * 4 + wv;   // global wave id 0..1023
    const int d0 = lane * 4;       // conflict-free lane chunk base
    int bk = 0;

    float* qkv_pre  = wsf;                   // [6][35][1536]
    float* msg_pre  = qkv_pre + 322560;      // [6][5][512]
    float* aggv_pre = msg_pre + 15360;       // [6][512]
    float* qkv0     = aggv_pre + 3072;       // [7][1536]
    float* msg0     = qkv0 + 10752;          // [6][512]  rows 1..6
    float* aggn     = msg0 + 3072;           // [512]
    float* hbuf     = aggn + 512;            // [7][2048]
    float* xlnws    = hbuf + 14336;          // [7][512]
    float* ffA      = xlnws + 3584;          // [7][512]
    float* ffB      = ffA + 3584;            // [7][512]

    // ================= P1: qkv for batches 1..5, ALL 6 layers =================
    for (int i = t; i < 35*ND; i += 256) {
        int m = i >> 9, d = i & 511;
        int b = m / 7 + 1, s = m - (m/7)*7;
        float v = features[(b*7+s)*ND + d];
        if (s > 0) v += role[(b*6 + s-1)*ND + d];
        lds[i] = v;
    }
    __syncthreads();
    for (int k = 0; k < 9; k++) {
        int p = gw + (k << 10);   // 0..9215
        int l, e; bool kv;
        if (p < 6144) { l = p >> 10; e = 512 + (p & 1023); kv = true; }
        else { int q = p - 6144; l = q >> 9; e = q & 511; kv = false; }
        const float* wr = in_w + ((size_t)l*1536 + e)*ND;
        float4 w1 = *(const float4*)(wr + d0), w2 = *(const float4*)(wr + 256 + d0);
        float bias = in_b[l*1536 + e];
        if (kv) {
            for (int m = 0; m < 35; m++) {
                float a = dot8L(&lds[m*ND], d0, w1, w2);
                a = wave_sum(a);
                if (lane == 0) cstore(&qkv_pre[((size_t)l*35 + m)*1536 + e], a + bias);
            }
        } else {
            for (int bb = 0; bb < 5; bb++) {
                int m = bb * 7;  // s=0 rows only (Q needed just for s=0)
                float a = dot8L(&lds[m*ND], d0, w1, w2);
                a = wave_sum(a);
                if (lane == 0) cstore(&qkv_pre[((size_t)l*35 + m)*1536 + e], a + bias);
            }
        }
    }
    gbar(bar, bk++);

    // ================= P2: attention + msg row (s=0) for b=1..5, all layers =====
    if (bid < 240) {
        int g = bid >> 3, sub = bid & 7;
        int l = g / 5, b = g - l*5 + 1;
        float* kl = lds;            // 7*512
        float* vl = lds + 3584;     // 7*512
        float* ql = lds + 7168;     // 512
        float* cl = lds + 7680;     // 512
        float* at = lds + 8192;     // 56
        size_t base = ((size_t)l*35 + (b-1)*7) * 1536;
        for (int i = t; i < 3584; i += 256) {
            int s = i >> 9, d = i & 511;
            kl[i] = cload(&qkv_pre[base + (size_t)s*1536 + 512 + d]);
            vl[i] = cload(&qkv_pre[base + (size_t)s*1536 + 1024 + d]);
        }
        for (int i = t; i < 512; i += 256) ql[i] = cload(&qkv_pre[base + i]);
        __syncthreads();
        if (t < 56) {
            int h = t / 7, kk = t - (t/7)*7;
            float a = 0.f;
            for (int i = 0; i < 64; i++) {
                int d = (i + t) & 63;        // lane-skew: avoid same-bank wave read
                a += ql[h*64 + d] * kl[kk*512 + h*64 + d];
            }
            at[t] = a * 0.125f;
        }
        __syncthreads();
        if (t < 8) {
            float m = -1e30f;
            for (int j = 0; j < 7; j++) m = fmaxf(m, at[t*7 + j]);
            float e[7], ss = 0.f;
            for (int j = 0; j < 7; j++) { e[j] = expf(at[t*7 + j] - m); ss += e[j]; }
            float inv = 1.f / ss;
            for (int j = 0; j < 7; j++) at[t*7 + j] = e[j] * inv;
        }
        __syncthreads();
        for (int i = t; i < 512; i += 256) {
            int h = i >> 6;
            float a = 0.f;
            for (int kk = 0; kk < 7; kk++) a += at[h*7 + kk] * vl[kk*512 + i];
            cl[i] = a;
        }
        __syncthreads();
        for (int i = 0; i < 16; i++) {
            int e = sub*64 + wv*16 + i;
            const float* wr = out_w + ((size_t)l*512 + e)*ND;
            float4 w1 = *(const float4*)(wr + d0), w2 = *(const float4*)(wr + 256 + d0);
            float a = dot8L(cl, d0, w1, w2);
            a = wave_sum(a);
            if (lane == 0) cstore(&msg_pre[((size_t)l*5 + b-1)*512 + e], a + out_b[l*512 + e]);
        }
    }
    gbar(bar, bk++);

    // ================= P3: agg_verb for all layers =================
    for (int k = 0; k < 3; k++) {
        int p = gw + (k << 10);   // 0..3071
        int l = p >> 9, j = p & 511;
        const float* wj = a1_w + (size_t)l*1310720 + (size_t)j*2560;
        float a = 0.f;
        for (int c = 0; c < 5; c++)
            a += dotc(msg_pre + ((size_t)l*5 + c)*512, wj + c*512, d0);
        a = wave_sum(a);
        if (lane == 0) cstore(&aggv_pre[l*512 + j], 1.f / (1.f + expf(-(a + a1_b[l*512 + j]))));
    }
    gbar(bar, bk++);

    // ================= sequential layer chain (batch 0) =================
    const float* ffprev = nullptr;
    #pragma unroll 1
    for (int l = 0; l < NL; l++) {
        float* ffcur = (l & 1) ? ffB : ffA;

        // ---- S1: build src rows (cur + role) in LDS, then qkv b0 ----
        for (int rr = wv; rr < 7; rr += 4) {
            float4 f1, f2;
            if (l == 0) {
                const float* sp = features + rr*ND;
                f1 = *(const float4*)(sp + d0); f2 = *(const float4*)(sp + 256 + d0);
            } else {
                cload8(ffprev + rr*ND, d0, f1, f2);
                float mu, inv; stats8(f1, f2, mu, inv);
                const float* w  = ((rr == 0) ? ln4_w : ln2_w) + (size_t)(l-1)*ND;
                const float* bb = ((rr == 0) ? ln4_b : ln2_b) + (size_t)(l-1)*ND;
                ln_apply(f1, f2, mu, inv, w, bb, d0);
            }
            if (rr > 0) {
                const float* rp = role + (size_t)(rr-1)*ND;
                float4 r1 = *(const float4*)(rp + d0), r2 = *(const float4*)(rp + 256 + d0);
                f1.x += r1.x; f1.y += r1.y; f1.z += r1.z; f1.w += r1.w;
                f2.x += r2.x; f2.y += r2.y; f2.z += r2.z; f2.w += r2.w;
            }
            *(float4*)&lds[rr*ND + d0] = f1;
            *(float4*)&lds[rr*ND + 256 + d0] = f2;
        }
        __syncthreads();
        for (int e = gw; e < 1536; e += 1024) {
            const float* wr = in_w + ((size_t)l*1536 + e)*ND;
            float4 w1 = *(const float4*)(wr + d0), w2 = *(const float4*)(wr + 256 + d0);
            float bias = in_b[l*1536 + e];
            for (int s = 0; s < 7; s++) {
                float a = dot8L(&lds[s*ND], d0, w1, w2);
                a = wave_sum(a);
                if (lane == 0) cstore(&qkv0[s*1536 + e], a + bias);
            }
        }
        gbar(bar, bk++);

        // ---- S2: attention b0 + msg rows 1..6 ----
        {
            float* kl = lds;             // 7*512
            float* vl = lds + 3584;      // 7*512
            float* ql = lds + 7168;      // 6*512 (q rows 1..6)
            float* cl = lds + 10240;     // 6*512 (ctx rows 1..6)
            float* at = lds + 13312;     // 336
            for (int i = t; i < 3584; i += 256) {
                int s = i >> 9, d = i & 511;
                kl[i] = cload(&qkv0[s*1536 + 512 + d]);
                vl[i] = cload(&qkv0[s*1536 + 1024 + d]);
            }
            for (int i = t; i < 3072; i += 256) {
                int s = (i >> 9) + 1;
                ql[i] = cload(&qkv0[s*1536 + (i & 511)]);
            }
            __syncthreads();
            for (int idx = t; idx < 336; idx += 256) {
                int qr = idx / 56, rem = idx - qr*56;
                int h = rem / 7, kk = rem - (rem/7)*7;
                float a = 0.f;
                for (int i = 0; i < 64; i++) {
                    int d = (i + (t & 63)) & 63;   // lane-skew
                    a += ql[qr*512 + h*64 + d] * kl[kk*512 + h*64 + d];
                }
                at[idx] = a * 0.125f;
            }
            __syncthreads();
            if (t < 48) {
                int qr = t >> 3, h = t & 7;
                float* ap = at + qr*56 + h*7;
                float m = -1e30f;
                for (int j = 0; j < 7; j++) m = fmaxf(m, ap[j]);
                float e[7], ss = 0.f;
                for (int j = 0; j < 7; j++) { e[j] = expf(ap[j] - m); ss += e[j]; }
                float inv = 1.f / ss;
                for (int j = 0; j < 7; j++) ap[j] = e[j] * inv;
            }
            __syncthreads();
            for (int i = t; i < 3072; i += 256) {
                int qr = i >> 9, d = i & 511, h = d >> 6;
                const float* ap = at + qr*56 + h*7;
                float a = 0.f;
                for (int kk = 0; kk < 7; kk++) a += ap[kk] * vl[kk*512 + d];
                cl[i] = a;
            }
            __syncthreads();
            for (int i = 0; i < 3; i++) {
                int o = bid*12 + wv*3 + i;      // 0..3071
                int s = o >> 9, e = o & 511;    // s = msg0 row idx 0..5
                const float* wr = out_w + ((size_t)l*512 + e)*ND;
                float4 w1 = *(const float4*)(wr + d0), w2 = *(const float4*)(wr + 256 + d0);
                float a = dot8L(&cl[s*512], d0, w1, w2);
                a = wave_sum(a);
                if (lane == 0) cstore(&msg0[s*512 + e], a + out_b[l*512 + e]);
            }
        }
        gbar(bar, bk++);

        // ---- S3: agg_noun (stage msg0 to LDS first) ----
        {
            for (int i = t; i < 3072; i += 256) lds[i] = cload(&msg0[i]);
            __syncthreads();
            int j = bid*2 + (wv >> 1), half = wv & 1;
            const float* wj = a2_w + (size_t)l*1572864 + (size_t)j*3072 + half*1536;
            float a = 0.f;
            for (int c = 0; c < 3; c++) {
                const float* wc = wj + c*512;
                float4 w1 = *(const float4*)(wc + d0), w2 = *(const float4*)(wc + 256 + d0);
                a += dot8L(&lds[(half*3 + c)*512], d0, w1, w2);
            }
            a = wave_sum(a);
            if (lane == 0) sred[wv] = a;
            __syncthreads();
            if (t == 0) {
                int j0 = bid*2;
                cstore(&aggn[j0],     1.f / (1.f + expf(-(sred[0] + sred[1] + a2_b[l*512 + j0]))));
                cstore(&aggn[j0 + 1], 1.f / (1.f + expf(-(sred[2] + sred[3] + a2_b[l*512 + j0 + 1]))));
            }
        }
        gbar(bar, bk++);

        // ---- S4: build xln rows in LDS; ffa ----
        for (int rr = wv; rr < 7; rr += 4) {
            float4 f1, f2;
            if (l == 0) {
                const float* sp = features + rr*ND;
                f1 = *(const float4*)(sp + d0); f2 = *(const float4*)(sp + 256 + d0);
            } else {
                cload8(ffprev + rr*ND, d0, f1, f2);
                float mu, inv; stats8(f1, f2, mu, inv);
                const float* w  = ((rr == 0) ? ln4_w : ln2_w) + (size_t)(l-1)*ND;
                const float* bb = ((rr == 0) ? ln4_b : ln2_b) + (size_t)(l-1)*ND;
                ln_apply(f1, f2, mu, inv, w, bb, d0);
            }
            const float* ag = (rr == 0) ? aggn : (aggv_pre + l*512);
            float4 g1, g2; cload8(ag, d0, g1, g2);
            f1.x += g1.x; f1.y += g1.y; f1.z += g1.z; f1.w += g1.w;
            f2.x += g2.x; f2.y += g2.y; f2.z += g2.z; f2.w += g2.w;
            float mu, inv; stats8(f1, f2, mu, inv);
            const float* w  = ((rr == 0) ? ln3_w : ln1_w) + (size_t)l*ND;
            const float* bb = ((rr == 0) ? ln3_b : ln1_b) + (size_t)l*ND;
            ln_apply(f1, f2, mu, inv, w, bb, d0);
            *(float4*)&lds[rr*ND + d0] = f1;
            *(float4*)&lds[rr*ND + 256 + d0] = f2;
        }
        __syncthreads();
        if (bid == 0) for (int i = t; i < 3584; i += 256) cstore(&xlnws[i], lds[i]);
        for (int i2 = 0; i2 < 2; i2++) {
            int f = bid*8 + wv*2 + i2;    // 0..2047
            const float* wr1 = f1_w1 + ((size_t)l*2048 + f)*ND;  // rows 1..6
            float4 p1 = *(const float4*)(wr1 + d0), p2 = *(const float4*)(wr1 + 256 + d0);
            const float* wr2 = f2_w1 + ((size_t)l*2048 + f)*ND;  // row 0
            float4 q1 = *(const float4*)(wr2 + d0), q2 = *(const float4*)(wr2 + 256 + d0);
            float a = dot8L(&lds[0], d0, q1, q2);
            a = wave_sum(a);
            if (lane == 0) cstore(&hbuf[f], fmaxf(a + f2_b1[l*2048 + f], 0.f));
            for (int r = 1; r < 7; r++) {
                float b2_ = dot8L(&lds[r*ND], d0, p1, p2);
                b2_ = wave_sum(b2_);
                if (lane == 0) cstore(&hbuf[r*2048 + f], fmaxf(b2_ + f1_b1[l*2048 + f], 0.f));
            }
        }
        gbar(bar, bk++);

        // ---- S5: ffb (+ residual); stage hbuf to LDS first ----
        {
            for (int i = t; i < 14336; i += 256) lds[i] = cload(&hbuf[i]);
            __syncthreads();
            int d = bid*2 + (wv >> 1);
            int rs = (wv & 1) ? 4 : 0, re = (wv & 1) ? 7 : 4;
            for (int r = rs; r < re; r++) {
                const float* W = ((r == 0) ? f2_w2 : f1_w2) + (size_t)l*1048576 + (size_t)d*2048;
                float a = 0.f;
                for (int c = 0; c < 4; c++) {
                    const float* wc = W + c*512;
                    float4 w1 = *(const float4*)(wc + d0), w2 = *(const float4*)(wc + 256 + d0);
                    a += dot8L(&lds[r*2048 + c*512], d0, w1, w2);
                }
                a = wave_sum(a);
                if (lane == 0) {
                    float bias = (r == 0) ? f2_b2[l*512 + d] : f1_b2[l*512 + d];
                    cstore(&ffcur[r*512 + d], cload(&xlnws[r*512 + d]) + a + bias);
                }
            }
        }
        ffprev = ffcur;
        gbar(bar, bk++);
    }

    // ================= F: final LN -> d_out =================
    if (bid < 7) {
        int r = bid;
        float x0 = cload(&ffprev[r*ND + t]), x1 = cload(&ffprev[r*ND + 256 + t]);
        float v = wave_sum(x0 + x1);
        if (lane == 0) sred[wv] = v;
        __syncthreads();
        float mu = (sred[0] + sred[1] + sred[2] + sred[3]) * (1.f/512.f);
        __syncthreads();
        float e0 = x0 - mu, e1 = x1 - mu;
        v = wave_sum(e0*e0 + e1*e1);
        if (lane == 0) sred[wv] = v;
        __syncthreads();
        float var = (sred[0] + sred[1] + sred[2] + sred[3]) * (1.f/512.f);
        float inv = rsqrtf(var + 1e-5f);
        const float* w  = ((r == 0) ? ln4_w : ln2_w) + (size_t)(NL-1)*ND;
        const float* bb = ((r == 0) ? ln4_b : ln2_b) + (size_t)(NL-1)*ND;
        outp[r*ND + t]       = e0*inv*w[t]       + bb[t];
        outp[r*ND + 256 + t] = e1*inv*w[256 + t] + bb[256 + t];
    }
}

extern "C" void kernel_launch(void* const* d_in, const int* in_sizes, int n_in,
                              void* d_out, int out_size, void* d_ws, size_t ws_size,
                              hipStream_t stream) {
    const float* features = (const float*)d_in[0];
    const float* role     = (const float*)d_in[1];
    const float* in_w  = (const float*)d_in[2];
    const float* in_b  = (const float*)d_in[3];
    const float* out_w = (const float*)d_in[4];
    const float* out_b = (const float*)d_in[5];
    const float* ln1_w = (const float*)d_in[6];
    const float* ln1_b = (const float*)d_in[7];
    const float* ln2_w = (const float*)d_in[8];
    const float* ln2_b = (const float*)d_in[9];
    const float* ln3_w = (const float*)d_in[10];
    const float* ln3_b = (const float*)d_in[11];
    const float* ln4_w = (const float*)d_in[12];
    const float* ln4_b = (const float*)d_in[13];
    const float* f1_w1 = (const float*)d_in[14];
    const float* f1_b1 = (const float*)d_in[15];
    const float* f1_w2 = (const float*)d_in[16];
    const float* f1_b2 = (const float*)d_in[17];
    const float* f2_w1 = (const float*)d_in[18];
    const float* f2_b1 = (const float*)d_in[19];
    const float* f2_w2 = (const float*)d_in[20];
    const float* f2_b2 = (const float*)d_in[21];
    const float* a1_w  = (const float*)d_in[22];
    const float* a1_b  = (const float*)d_in[23];
    const float* a2_w  = (const float*)d_in[24];
    const float* a2_b  = (const float*)d_in[25];

    // barrier state: first 4 KB of ws, zeroed every call (monotonic counters)
    hipMemsetAsync(d_ws, 0, 4096, stream);
    unsigned* bar = (unsigned*)d_ws;
    float* wsf = (float*)d_ws + 1024;

    fused_persistent<<<256, 256, 0, stream>>>(
        features, role, in_w, in_b, out_w, out_b,
        ln1_w, ln1_b, ln2_w, ln2_b, ln3_w, ln3_b, ln4_w, ln4_b,
        f1_w1, f1_b1, f1_w2, f1_b2, f2_w1, f2_b1, f2_w2, f2_b2,
        a1_w, a1_b, a2_w, a2_b,
        bar, wsf, (float*)d_out);
}

// Round 7
// 643.319 us; speedup vs baseline: 2.5319x; 1.2208x over previous
//
#include <hip/hip_runtime.h>
#include <math.h>

#define NL 6
#define ND 512
#define NFF 2048

// ---------- coherent scalar access (L2-bypassing, safe cross-XCD) ----------
__device__ __forceinline__ float cload(const float* p) {
    return __hip_atomic_load(p, __ATOMIC_RELAXED, __HIP_MEMORY_SCOPE_AGENT);
}
__device__ __forceinline__ void cstore(float* p, float v) {
    __hip_atomic_store(p, v, __ATOMIC_RELAXED, __HIP_MEMORY_SCOPE_AGENT);
}
// ---------- coherent vector LOADS via inline asm (128-bit outputs are OK) ----------
__device__ __forceinline__ float4 cload4(const float* p) {
    float4 r;
    asm volatile("global_load_dwordx4 %0, %1, off sc0 sc1\n"
                 "s_waitcnt vmcnt(0)"
                 : "=v"(r) : "v"(p) : "memory");
    return r;
}
__device__ __forceinline__ void cload4x2(const float* p0, const float* p1, float4& a, float4& b) {
    asm volatile("global_load_dwordx4 %0, %2, off sc0 sc1\n"
                 "global_load_dwordx4 %1, %3, off sc0 sc1\n"
                 "s_waitcnt vmcnt(0)"
                 : "=&v"(a), "=&v"(b) : "v"(p0), "v"(p1) : "memory");
}
// coherent 4-dword store: scalar components (float4 inline-asm INPUT unsupported).
// Stores are fire-and-forget; latency doesn't chain. Drained by gbar's vmcnt(0).
__device__ __forceinline__ void cstore4(float* p, float4 v) {
    __hip_atomic_store(p,     v.x, __ATOMIC_RELAXED, __HIP_MEMORY_SCOPE_AGENT);
    __hip_atomic_store(p + 1, v.y, __ATOMIC_RELAXED, __HIP_MEMORY_SCOPE_AGENT);
    __hip_atomic_store(p + 2, v.z, __ATOMIC_RELAXED, __HIP_MEMORY_SCOPE_AGENT);
    __hip_atomic_store(p + 3, v.w, __ATOMIC_RELAXED, __HIP_MEMORY_SCOPE_AGENT);
}
// stage ndw dwords (16B-aligned, ndw%4==0) coherent global -> LDS, 256 threads
__device__ __forceinline__ void stageC(float* dst, const float* src, int ndw) {
    int n4 = ndw >> 2;
    int i = threadIdx.x;
    for (; i + 768 < n4; i += 1024) {
        float4 a, b, c, d;
        asm volatile(
            "global_load_dwordx4 %0, %4, off sc0 sc1\n"
            "global_load_dwordx4 %1, %5, off sc0 sc1\n"
            "global_load_dwordx4 %2, %6, off sc0 sc1\n"
            "global_load_dwordx4 %3, %7, off sc0 sc1\n"
            "s_waitcnt vmcnt(0)"
            : "=&v"(a), "=&v"(b), "=&v"(c), "=&v"(d)
            : "v"(src + i*4), "v"(src + (i+256)*4), "v"(src + (i+512)*4), "v"(src + (i+768)*4)
            : "memory");
        *(float4*)(dst + i*4) = a;
        *(float4*)(dst + (i+256)*4) = b;
        *(float4*)(dst + (i+512)*4) = c;
        *(float4*)(dst + (i+768)*4) = d;
    }
    for (; i < n4; i += 256) {
        float4 a = cload4(src + i*4);
        *(float4*)(dst + i*4) = a;
    }
}
// LDS -> coherent global
__device__ __forceinline__ void storeC(float* dst, const float* src_lds, int ndw) {
    for (int i4 = threadIdx.x; i4 < (ndw >> 2); i4 += 256)
        cstore4(dst + i4*4, *(const float4*)(src_lds + i4*4));
}

// ---------- wave helpers ----------
__device__ __forceinline__ float wave_sum(float v) {
    v += __shfl_down(v, 32, 64);
    v += __shfl_down(v, 16, 64);
    v += __shfl_down(v, 8, 64);
    v += __shfl_down(v, 4, 64);
    v += __shfl_down(v, 2, 64);
    v += __shfl_down(v, 1, 64);
    return v;
}
__device__ __forceinline__ float wave_sum_all(float v) {
    v += __shfl_xor(v, 32, 64);
    v += __shfl_xor(v, 16, 64);
    v += __shfl_xor(v, 8, 64);
    v += __shfl_xor(v, 4, 64);
    v += __shfl_xor(v, 2, 64);
    v += __shfl_xor(v, 1, 64);
    return v;
}
// lane handles dwords [d0,d0+3] and [256+d0,...] ; d0=4*lane (conflict-free b128)
__device__ __forceinline__ float dot8L(const float* a, int d0, float4 w1, float4 w2) {
    float4 x1 = *(const float4*)(a + d0);
    float4 x2 = *(const float4*)(a + 256 + d0);
    return x1.x*w1.x + x1.y*w1.y + x1.z*w1.z + x1.w*w1.w
         + x2.x*w2.x + x2.y*w2.y + x2.z*w2.z + x2.w*w2.w;
}
__device__ __forceinline__ void cload8v(const float* p, int d0, float4& f1, float4& f2) {
    cload4x2(p + d0, p + 256 + d0, f1, f2);
}
__device__ __forceinline__ float dotcv(const float* ac, const float* w, int d0) {
    float4 a1, a2; cload4x2(ac + d0, ac + 256 + d0, a1, a2);
    float4 w1 = *(const float4*)(w + d0), w2 = *(const float4*)(w + 256 + d0);
    return a1.x*w1.x + a1.y*w1.y + a1.z*w1.z + a1.w*w1.w
         + a2.x*w2.x + a2.y*w2.y + a2.z*w2.z + a2.w*w2.w;
}
__device__ __forceinline__ void stats8(float4 f1, float4 f2, float& mu, float& inv) {
    float s = f1.x+f1.y+f1.z+f1.w + f2.x+f2.y+f2.z+f2.w;
    s = wave_sum_all(s);
    mu = s * (1.f/512.f);
    float q = (f1.x-mu)*(f1.x-mu) + (f1.y-mu)*(f1.y-mu) + (f1.z-mu)*(f1.z-mu) + (f1.w-mu)*(f1.w-mu)
            + (f2.x-mu)*(f2.x-mu) + (f2.y-mu)*(f2.y-mu) + (f2.z-mu)*(f2.z-mu) + (f2.w-mu)*(f2.w-mu);
    q = wave_sum_all(q);
    inv = rsqrtf(q * (1.f/512.f) + 1e-5f);
}
__device__ __forceinline__ void ln_apply(float4& f1, float4& f2, float mu, float inv,
                                         const float* __restrict__ w,
                                         const float* __restrict__ b, int d0) {
    float4 w1 = *(const float4*)(w + d0), w2 = *(const float4*)(w + 256 + d0);
    float4 b1 = *(const float4*)(b + d0), b2 = *(const float4*)(b + 256 + d0);
    f1.x = (f1.x-mu)*inv*w1.x + b1.x; f1.y = (f1.y-mu)*inv*w1.y + b1.y;
    f1.z = (f1.z-mu)*inv*w1.z + b1.z; f1.w = (f1.w-mu)*inv*w1.w + b1.w;
    f2.x = (f2.x-mu)*inv*w2.x + b2.x; f2.y = (f2.y-mu)*inv*w2.y + b2.y;
    f2.z = (f2.z-mu)*inv*w2.z + b2.z; f2.w = (f2.w-mu)*inv*w2.w + b2.w;
}
__device__ __forceinline__ float sigm(float x) { return 1.f / (1.f + expf(-x)); }

// ---------- grid barrier: no cache maintenance (data path is coherent) ----------
__device__ __forceinline__ void gbar(unsigned* bar, int k) {
    asm volatile("s_waitcnt vmcnt(0) lgkmcnt(0)" ::: "memory");
    __syncthreads();
    if (threadIdx.x == 0) {
        int sub = blockIdx.x & 7;
        unsigned v = __hip_atomic_fetch_add(&bar[sub*32], 1u, __ATOMIC_RELAXED, __HIP_MEMORY_SCOPE_AGENT);
        if (v == 32u*(unsigned)(k+1) - 1u) {
            unsigned tt = __hip_atomic_fetch_add(&bar[512], 1u, __ATOMIC_RELAXED, __HIP_MEMORY_SCOPE_AGENT);
            if (tt == 8u*(unsigned)(k+1) - 1u)
                __hip_atomic_store(&bar[768], (unsigned)(k+1), __ATOMIC_RELAXED, __HIP_MEMORY_SCOPE_AGENT);
        }
        while (__hip_atomic_load(&bar[768], __ATOMIC_RELAXED, __HIP_MEMORY_SCOPE_AGENT) < (unsigned)(k+1))
            __builtin_amdgcn_s_sleep(1);
    }
    __syncthreads();
}

__global__ __launch_bounds__(256, 2)
void fused_persistent(const float* __restrict__ features, const float* __restrict__ role,
                      const float* __restrict__ in_w,  const float* __restrict__ in_b,
                      const float* __restrict__ out_w, const float* __restrict__ out_b,
                      const float* __restrict__ ln1_w, const float* __restrict__ ln1_b,
                      const float* __restrict__ ln2_w, const float* __restrict__ ln2_b,
                      const float* __restrict__ ln3_w, const float* __restrict__ ln3_b,
                      const float* __restrict__ ln4_w, const float* __restrict__ ln4_b,
                      const float* __restrict__ f1_w1, const float* __restrict__ f1_b1,
                      const float* __restrict__ f1_w2, const float* __restrict__ f1_b2,
                      const float* __restrict__ f2_w1, const float* __restrict__ f2_b1,
                      const float* __restrict__ f2_w2, const float* __restrict__ f2_b2,
                      const float* __restrict__ a1_w,  const float* __restrict__ a1_b,
                      const float* __restrict__ a2_w,  const float* __restrict__ a2_b,
                      unsigned* bar, float* wsf, float* __restrict__ outp)
{
    __shared__ float lds[18432];   // 72 KB, reused per phase
    __shared__ float sred[16];
    const int t = threadIdx.x, bid = blockIdx.x;
    const int wv = t >> 6, lane = t & 63;
    const int gw = bid * 4 + wv;   // 0..1023
    const int d0 = lane * 4;
    int bk = 0;

    float* qkv_pre  = wsf;                   // [6][35][1536]
    float* msg_pre  = qkv_pre + 322560;      // [6][5][512]
    float* aggv_pre = msg_pre + 15360;       // [6][512]
    float* qkv0     = aggv_pre + 3072;       // [7][1536]
    float* msg0     = qkv0 + 10752;          // [6][512] (rows 1..6)
    float* aggn     = msg0 + 3072;           // [512]
    float* hbuf     = aggn + 512;            // [7][2048]
    float* xlnws    = hbuf + 14336;          // [7][512]
    float* ffA      = xlnws + 3584;          // [7][512]
    float* ffB      = ffA + 3584;            // [7][512]

    float4 wq[6], wpC[6], wpD[4], wpE[4];

    // ================= P1: qkv for batches 1..5, ALL 6 layers =================
    for (int i = t; i < 35*ND; i += 256) {
        int m = i >> 9, d = i & 511;
        int b = m / 7 + 1, s = m - (m/7)*7;
        float v = features[(b*7+s)*ND + d];
        if (s > 0) v += role[(b*6 + s-1)*ND + d];
        lds[i] = v;
    }
    __syncthreads();
    for (int k = 0; k < 9; k++) {
        int p = gw + (k << 10);   // 0..9215
        int l, e; bool kv;
        if (p < 6144) { l = p >> 10; e = 512 + (p & 1023); kv = true; }
        else { int q = p - 6144; l = q >> 9; e = q & 511; kv = false; }
        const float* wr = in_w + ((size_t)l*1536 + e)*ND;
        float4 w1 = *(const float4*)(wr + d0), w2 = *(const float4*)(wr + 256 + d0);
        float bias = in_b[l*1536 + e];
        if (kv) {
            for (int m = 0; m < 35; m++) {
                float a = dot8L(&lds[m*ND], d0, w1, w2);
                a = wave_sum(a);
                if (lane == 0) cstore(&qkv_pre[((size_t)l*35 + m)*1536 + e], a + bias);
            }
        } else {
            for (int bb = 0; bb < 5; bb++) {
                int m = bb * 7;
                float a = dot8L(&lds[m*ND], d0, w1, w2);
                a = wave_sum(a);
                if (lane == 0) cstore(&qkv_pre[((size_t)l*35 + m)*1536 + e], a + bias);
            }
        }
    }
    gbar(bar, bk++);

    // ================= P2: attention + msg(s=0) for b=1..5, all layers =================
    if (bid < 240) {
        int g = bid >> 3, sub = bid & 7;
        int l = g / 5, b = g - l*5 + 1;
        float* kl = lds;            // 7*512
        float* vl = lds + 3584;     // 7*512
        float* ql = lds + 7168;     // 512
        float* cl = lds + 7680;     // 512
        float* at = lds + 8192;     // 56
        const float* base = qkv_pre + ((size_t)l*35 + (b-1)*7) * 1536;
        for (int i4 = t; i4 < 896; i4 += 256) {
            int idx = i4*4, s = idx >> 9, d = idx & 511;
            float4 a, b2;
            cload4x2(base + s*1536 + 512 + d, base + s*1536 + 1024 + d, a, b2);
            *(float4*)(kl + idx) = a; *(float4*)(vl + idx) = b2;
        }
        for (int i4 = t; i4 < 128; i4 += 256) {
            float4 a = cload4(base + i4*4);
            *(float4*)(ql + i4*4) = a;
        }
        __syncthreads();
        if (t < 56) {
            int h = t / 7, kk = t - (t/7)*7;
            float a = 0.f;
            for (int i = 0; i < 64; i++) {
                int d = (i + t) & 63;
                a += ql[h*64 + d] * kl[kk*512 + h*64 + d];
            }
            at[t] = a * 0.125f;
        }
        __syncthreads();
        if (t < 8) {
            float m = -1e30f;
            for (int j = 0; j < 7; j++) m = fmaxf(m, at[t*7 + j]);
            float e[7], ss = 0.f;
            for (int j = 0; j < 7; j++) { e[j] = expf(at[t*7 + j] - m); ss += e[j]; }
            float inv = 1.f / ss;
            for (int j = 0; j < 7; j++) at[t*7 + j] = e[j] * inv;
        }
        __syncthreads();
        for (int i = t; i < 512; i += 256) {
            int h = i >> 6;
            float a = 0.f;
            for (int kk = 0; kk < 7; kk++) a += at[h*7 + kk] * vl[kk*512 + i];
            cl[i] = a;
        }
        __syncthreads();
        #pragma unroll
        for (int i = 0; i < 16; i++) {
            int e = sub*64 + wv*16 + i;
            const float* wr = out_w + ((size_t)l*512 + e)*ND;
            float4 w1 = *(const float4*)(wr + d0), w2 = *(const float4*)(wr + 256 + d0);
            float a = dot8L(cl, d0, w1, w2);
            a = wave_sum(a);
            if (lane == 0) cstore(&msg_pre[((size_t)l*5 + b-1)*512 + e], a + out_b[l*512 + e]);
        }
    }
    gbar(bar, bk++);

    // ================= P3: agg_verb for all layers =================
    for (int k = 0; k < 3; k++) {
        int p = gw + (k << 10);   // 0..3071
        int l = p >> 9, j = p & 511;
        const float* wj = a1_w + (size_t)l*1310720 + (size_t)j*2560;
        float a = 0.f;
        #pragma unroll
        for (int c = 0; c < 5; c++)
            a += dotcv(msg_pre + ((size_t)l*5 + c)*512, wj + c*512, d0);
        a = wave_sum(a);
        if (lane == 0) cstore(&aggv_pre[l*512 + j], sigm(a + a1_b[l*512 + j]));
    }
    // prefetch phase-A(l=0) qkv weights
    if (bid < 128) {
        int gw2 = bid*4 + wv;
        #pragma unroll
        for (int k2 = 0; k2 < 3; k2++) {
            int e = gw2 + (k2 << 9);
            const float* wr = in_w + (size_t)e*ND;
            wq[2*k2]   = *(const float4*)(wr + d0);
            wq[2*k2+1] = *(const float4*)(wr + 256 + d0);
        }
    }
    gbar(bar, bk++);

    // ================= sequential layer chain =================
    const float* ffprev = nullptr;
    #pragma unroll 1
    for (int l = 0; l < NL; l++) {
        float* ffcur = (l & 1) ? ffB : ffA;

        // ---- A: qkv0 (blocks 0..127)  ||  ffa rows 1..6 (blocks 128..255) ----
        if (bid < 128) {
            for (int rr = wv; rr < 7; rr += 4) {
                float4 f1, f2;
                if (l == 0) {
                    const float* sp = features + rr*ND;
                    f1 = *(const float4*)(sp + d0); f2 = *(const float4*)(sp + 256 + d0);
                } else {
                    cload8v(ffprev + rr*ND, d0, f1, f2);
                    float mu, inv; stats8(f1, f2, mu, inv);
                    const float* w  = ((rr == 0) ? ln4_w : ln2_w) + (size_t)(l-1)*ND;
                    const float* bb = ((rr == 0) ? ln4_b : ln2_b) + (size_t)(l-1)*ND;
                    ln_apply(f1, f2, mu, inv, w, bb, d0);
                }
                if (rr > 0) {
                    const float* rp = role + (size_t)(rr-1)*ND;
                    float4 r1 = *(const float4*)(rp + d0), r2 = *(const float4*)(rp + 256 + d0);
                    f1.x += r1.x; f1.y += r1.y; f1.z += r1.z; f1.w += r1.w;
                    f2.x += r2.x; f2.y += r2.y; f2.z += r2.z; f2.w += r2.w;
                }
                *(float4*)&lds[rr*ND + d0] = f1;
                *(float4*)&lds[rr*ND + 256 + d0] = f2;
            }
            __syncthreads();
            int gw2 = bid*4 + wv;
            #pragma unroll
            for (int k2 = 0; k2 < 3; k2++) {
                int e = gw2 + (k2 << 9);
                float bias = in_b[l*1536 + e];
                for (int s = 0; s < 7; s++) {
                    float a = dot8L(&lds[s*ND], d0, wq[2*k2], wq[2*k2+1]);
                    a = wave_sum(a);
                    if (lane == 0) cstore(&qkv0[s*1536 + e], a + bias);
                }
            }
        } else {
            for (int rr = wv; rr < 6; rr += 4) {
                int r = rr + 1;
                float4 f1, f2;
                if (l == 0) {
                    const float* sp = features + r*ND;
                    f1 = *(const float4*)(sp + d0); f2 = *(const float4*)(sp + 256 + d0);
                } else {
                    cload8v(ffprev + r*ND, d0, f1, f2);
                    float mu, inv; stats8(f1, f2, mu, inv);
                    const float* w  = ln2_w + (size_t)(l-1)*ND;
                    const float* bb = ln2_b + (size_t)(l-1)*ND;
                    ln_apply(f1, f2, mu, inv, w, bb, d0);
                }
                float4 g1, g2; cload8v(aggv_pre + l*512, d0, g1, g2);
                f1.x += g1.x; f1.y += g1.y; f1.z += g1.z; f1.w += g1.w;
                f2.x += g2.x; f2.y += g2.y; f2.z += g2.z; f2.w += g2.w;
                float mu, inv; stats8(f1, f2, mu, inv);
                ln_apply(f1, f2, mu, inv, ln1_w + (size_t)l*ND, ln1_b + (size_t)l*ND, d0);
                *(float4*)&lds[rr*ND + d0] = f1;
                *(float4*)&lds[rr*ND + 256 + d0] = f2;
            }
            __syncthreads();
            if (bid == 128) storeC(xlnws + 512, lds, 3072);
            int bb2 = bid - 128;
            #pragma unroll
            for (int j = 0; j < 4; j++) {
                int f = bb2*16 + wv*4 + j;
                const float* wr = f1_w1 + ((size_t)l*2048 + f)*ND;
                float4 w1 = *(const float4*)(wr + d0), w2 = *(const float4*)(wr + 256 + d0);
                float bias = f1_b1[l*2048 + f];
                for (int r = 0; r < 6; r++) {
                    float a = dot8L(&lds[r*ND], d0, w1, w2);
                    a = wave_sum(a);
                    if (lane == 0) cstore(&hbuf[(r+1)*2048 + f], fmaxf(a + bias, 0.f));
                }
            }
        }
        gbar(bar, bk++);

        // ---- B: attn+msg0 (blocks 0..63)  ||  ffb rows 1..6 (blocks 64..255) ----
        if (bid < 64) {
            float* kl = lds;             // 7*512
            float* vl = lds + 3584;      // 7*512
            float* ql = lds + 7168;      // 6*512
            float* cl = lds + 10240;     // 6*512
            float* at = lds + 13312;     // 336
            for (int i4 = t; i4 < 896; i4 += 256) {
                int idx = i4*4, s = idx >> 9, d = idx & 511;
                float4 a, b2;
                cload4x2(qkv0 + s*1536 + 512 + d, qkv0 + s*1536 + 1024 + d, a, b2);
                *(float4*)(kl + idx) = a; *(float4*)(vl + idx) = b2;
            }
            for (int i4 = t; i4 < 768; i4 += 256) {
                int idx = i4*4, s = (idx >> 9) + 1, d = idx & 511;
                float4 a = cload4(qkv0 + s*1536 + d);
                *(float4*)(ql + idx) = a;
            }
            __syncthreads();
            for (int idx = t; idx < 336; idx += 256) {
                int qr = idx / 56, rem = idx - qr*56;
                int h = rem / 7, kk = rem - (rem/7)*7;
                float a = 0.f;
                for (int i = 0; i < 64; i++) {
                    int d = (i + (t & 63)) & 63;
                    a += ql[qr*512 + h*64 + d] * kl[kk*512 + h*64 + d];
                }
                at[idx] = a * 0.125f;
            }
            __syncthreads();
            if (t < 48) {
                int qr = t >> 3, h = t & 7;
                float* ap = at + qr*56 + h*7;
                float m = -1e30f;
                for (int j = 0; j < 7; j++) m = fmaxf(m, ap[j]);
                float e[7], ss = 0.f;
                for (int j = 0; j < 7; j++) { e[j] = expf(ap[j] - m); ss += e[j]; }
                float inv = 1.f / ss;
                for (int j = 0; j < 7; j++) ap[j] = e[j] * inv;
            }
            __syncthreads();
            for (int i = t; i < 3072; i += 256) {
                int qr = i >> 9, d = i & 511, h = d >> 6;
                const float* ap = at + qr*56 + h*7;
                float a = 0.f;
                for (int kk = 0; kk < 7; kk++) a += ap[kk] * vl[kk*512 + d];
                cl[i] = a;
            }
            __syncthreads();
            #pragma unroll
            for (int i = 0; i < 12; i++) {
                int o = bid*48 + wv*12 + i;        // 0..3071
                int rm = o >> 9, e = o & 511;
                const float* wr = out_w + ((size_t)l*512 + e)*ND;
                float4 w1 = *(const float4*)(wr + d0), w2 = *(const float4*)(wr + 256 + d0);
                float a = dot8L(&cl[rm*512], d0, w1, w2);
                a = wave_sum(a);
                if (lane == 0) cstore(&msg0[o], a + out_b[l*512 + e]);
            }
        } else {
            stageC(lds, hbuf + 2048, 12288);       // rows 1..6
            __syncthreads();
            int bb2 = bid - 64;
            #pragma unroll
            for (int i = 0; i < 4; i++) {
                int o = bb2*16 + wv*4 + i;         // 0..3071
                int rm = o >> 9, dd = o & 511;     // rm = r-1
                const float* W = f1_w2 + (size_t)l*1048576 + (size_t)dd*2048;
                float acc = 0.f;
                #pragma unroll
                for (int c = 0; c < 4; c++) {
                    const float* wc = W + c*512;
                    float4 w1 = *(const float4*)(wc + d0), w2 = *(const float4*)(wc + 256 + d0);
                    acc += dot8L(&lds[rm*2048 + c*512], d0, w1, w2);
                }
                acc = wave_sum(acc);
                if (lane == 0)
                    cstore(&ffcur[(rm+1)*512 + dd],
                           cload(&xlnws[(rm+1)*512 + dd]) + acc + f1_b2[l*512 + dd]);
            }
        }
        // prefetch C weights (agg_noun)
        {
            int j = bid*2 + (wv >> 1), half = wv & 1;
            const float* wj = a2_w + (size_t)l*1572864 + (size_t)j*3072 + half*1536;
            #pragma unroll
            for (int c = 0; c < 3; c++) {
                const float* wc = wj + c*512;
                wpC[2*c]   = *(const float4*)(wc + d0);
                wpC[2*c+1] = *(const float4*)(wc + 256 + d0);
            }
        }
        gbar(bar, bk++);

        // ---- C: agg_noun (all blocks) ----
        stageC(lds, msg0, 3072);
        __syncthreads();
        {
            int half = wv & 1;
            float acc = 0.f;
            #pragma unroll
            for (int c = 0; c < 3; c++)
                acc += dot8L(&lds[(half*3 + c)*512], d0, wpC[2*c], wpC[2*c+1]);
            acc = wave_sum(acc);
            if (lane == 0) sred[wv] = acc;
        }
        __syncthreads();
        if (t == 0) {
            int j0 = bid*2;
            cstore(&aggn[j0],     sigm(sred[0] + sred[1] + a2_b[l*512 + j0]));
            cstore(&aggn[j0 + 1], sigm(sred[2] + sred[3] + a2_b[l*512 + j0 + 1]));
        }
        // prefetch D weights (ffa row 0)
        #pragma unroll
        for (int i2 = 0; i2 < 2; i2++) {
            int f = bid*8 + wv*2 + i2;
            const float* wr = f2_w1 + ((size_t)l*2048 + f)*ND;
            wpD[2*i2]   = *(const float4*)(wr + d0);
            wpD[2*i2+1] = *(const float4*)(wr + 256 + d0);
        }
        gbar(bar, bk++);

        // ---- D: ffa row 0 (all blocks; wave 0 builds xln0) ----
        if (wv == 0) {
            float4 f1, f2;
            if (l == 0) {
                f1 = *(const float4*)(features + d0); f2 = *(const float4*)(features + 256 + d0);
            } else {
                cload8v(ffprev, d0, f1, f2);
                float mu, inv; stats8(f1, f2, mu, inv);
                ln_apply(f1, f2, mu, inv, ln4_w + (size_t)(l-1)*ND, ln4_b + (size_t)(l-1)*ND, d0);
            }
            float4 g1, g2; cload8v(aggn, d0, g1, g2);
            f1.x += g1.x; f1.y += g1.y; f1.z += g1.z; f1.w += g1.w;
            f2.x += g2.x; f2.y += g2.y; f2.z += g2.z; f2.w += g2.w;
            float mu, inv; stats8(f1, f2, mu, inv);
            ln_apply(f1, f2, mu, inv, ln3_w + (size_t)l*ND, ln3_b + (size_t)l*ND, d0);
            *(float4*)&lds[d0] = f1;
            *(float4*)&lds[256 + d0] = f2;
        }
        __syncthreads();
        if (bid == 0 && t < 128) cstore4(xlnws + t*4, *(const float4*)&lds[t*4]);
        #pragma unroll
        for (int i2 = 0; i2 < 2; i2++) {
            int f = bid*8 + wv*2 + i2;
            float a = dot8L(lds, d0, wpD[2*i2], wpD[2*i2+1]);
            a = wave_sum(a);
            if (lane == 0) cstore(&hbuf[f], fmaxf(a + f2_b1[l*2048 + f], 0.f));
        }
        // prefetch E weights (ffb row 0)
        {
            int dd = bid*2 + (wv >> 1), half = wv & 1;
            #pragma unroll
            for (int c = 0; c < 2; c++) {
                const float* wc = f2_w2 + (size_t)l*1048576 + (size_t)dd*2048 + (half*2 + c)*512;
                wpE[2*c]   = *(const float4*)(wc + d0);
                wpE[2*c+1] = *(const float4*)(wc + 256 + d0);
            }
        }
        gbar(bar, bk++);

        // ---- E: ffb row 0 (all blocks) ----
        stageC(lds, hbuf, 2048);
        __syncthreads();
        {
            int half = wv & 1;
            float acc = 0.f;
            #pragma unroll
            for (int c = 0; c < 2; c++)
                acc += dot8L(&lds[(half*2 + c)*512], d0, wpE[2*c], wpE[2*c+1]);
            acc = wave_sum(acc);
            if (lane == 0) sred[wv] = acc;
        }
        __syncthreads();
        if (t == 0) {
            int dd0 = bid*2;
            cstore(&ffcur[dd0],     cload(&xlnws[dd0])     + sred[0] + sred[1] + f2_b2[l*512 + dd0]);
            cstore(&ffcur[dd0 + 1], cload(&xlnws[dd0 + 1]) + sred[2] + sred[3] + f2_b2[l*512 + dd0 + 1]);
        }
        ffprev = ffcur;
        // prefetch next layer's A qkv weights
        if (bid < 128 && l + 1 < NL) {
            int gw2 = bid*4 + wv;
            #pragma unroll
            for (int k2 = 0; k2 < 3; k2++) {
                int e = gw2 + (k2 << 9);
                const float* wr = in_w + ((size_t)(l+1)*1536 + e)*ND;
                wq[2*k2]   = *(const float4*)(wr + d0);
                wq[2*k2+1] = *(const float4*)(wr + 256 + d0);
            }
        }
        gbar(bar, bk++);
    }

    // ================= F: final LN -> d_out =================
    if (bid < 7) {
        int r = bid;
        float x0 = cload(&ffprev[r*ND + t]), x1 = cload(&ffprev[r*ND + 256 + t]);
        float v = wave_sum(x0 + x1);
        if (lane == 0) sred[wv] = v;
        __syncthreads();
        float mu = (sred[0] + sred[1] + sred[2] + sred[3]) * (1.f/512.f);
        __syncthreads();
        float e0 = x0 - mu, e1 = x1 - mu;
        v = wave_sum(e0*e0 + e1*e1);
        if (lane == 0) sred[wv] = v;
        __syncthreads();
        float var = (sred[0] + sred[1] + sred[2] + sred[3]) * (1.f/512.f);
        float inv = rsqrtf(var + 1e-5f);
        const float* w  = ((r == 0) ? ln4_w : ln2_w) + (size_t)(NL-1)*ND;
        const float* bb = ((r == 0) ? ln4_b : ln2_b) + (size_t)(NL-1)*ND;
        outp[r*ND + t]       = e0*inv*w[t]       + bb[t];
        outp[r*ND + 256 + t] = e1*inv*w[256 + t] + bb[256 + t];
    }
}

extern "C" void kernel_launch(void* const* d_in, const int* in_sizes, int n_in,
                              void* d_out, int out_size, void* d_ws, size_t ws_size,
                              hipStream_t stream) {
    const float* features = (const float*)d_in[0];
    const float* role     = (const float*)d_in[1];
    const float* in_w  = (const float*)d_in[2];
    const float* in_b  = (const float*)d_in[3];
    const float* out_w = (const float*)d_in[4];
    const float* out_b = (const float*)d_in[5];
    const float* ln1_w = (const float*)d_in[6];
    const float* ln1_b = (const float*)d_in[7];
    const float* ln2_w = (const float*)d_in[8];
    const float* ln2_b = (const float*)d_in[9];
    const float* ln3_w = (const float*)d_in[10];
    const float* ln3_b = (const float*)d_in[11];
    const float* ln4_w = (const float*)d_in[12];
    const float* ln4_b = (const float*)d_in[13];
    const float* f1_w1 = (const float*)d_in[14];
    const float* f1_b1 = (const float*)d_in[15];
    const float* f1_w2 = (const float*)d_in[16];
    const float* f1_b2 = (const float*)d_in[17];
    const float* f2_w1 = (const float*)d_in[18];
    const float* f2_b1 = (const float*)d_in[19];
    const float* f2_w2 = (const float*)d_in[20];
    const float* f2_b2 = (const float*)d_in[21];
    const float* a1_w  = (const float*)d_in[22];
    const float* a1_b  = (const float*)d_in[23];
    const float* a2_w  = (const float*)d_in[24];
    const float* a2_b  = (const float*)d_in[25];

    (void)hipMemsetAsync(d_ws, 0, 4096, stream);
    unsigned* bar = (unsigned*)d_ws;
    float* wsf = (float*)d_ws + 1024;

    fused_persistent<<<256, 256, 0, stream>>>(
        features, role, in_w, in_b, out_w, out_b,
        ln1_w, ln1_b, ln2_w, ln2_b, ln3_w, ln3_b, ln4_w, ln4_b,
        f1_w1, f1_b1, f1_w2, f1_b2, f2_w1, f2_b1, f2_w2, f2_b2,
        a1_w, a1_b, a2_w, a2_b,
        bar, wsf, (float*)d_out);
}